// Round 8
// baseline (160.232 us; speedup 1.0000x reference)
//
#include <hip/hip_runtime.h>
#include <math.h>

#define N_DET 1344
#define MW_MAX 8     // fast path supports M <= 512
#define T2S 9        // padded LDS row stride (u64) — breaks bank conflicts
#define QCAP 2048    // per-block needy-pair queue
#define PAIR_BLOCKS 256

// ---------------- device helpers ----------------

__device__ __forceinline__ bool pt_in_quad4(const float* qx, const float* qy,
                                            float px, float py) {
    bool allp = true, alln = true;
#pragma unroll
    for (int k = 0; k < 4; k++) {
        int k1 = (k + 1) & 3;
        float ex = qx[k1] - qx[k], ey = qy[k1] - qy[k];
        float rx = px - qx[k],     ry = py - qy[k];
        float cr = ex * ry - ey * rx;
        allp = allp && (cr >= 0.f);
        alln = alln && (cr <= 0.f);
    }
    return allp || alln;
}

// Exact fp-order-matched intersection area (register-only bitonic sort).
__device__ float quad_inter_area(const float* Ax, const float* Ay,
                                 const float* Bx, const float* By) {
    float px[24], py[24];
    unsigned vmask = 0;
    int n = 0;
#pragma unroll
    for (int k = 0; k < 4; k++) {
        px[k] = Ax[k]; py[k] = Ay[k];
        if (pt_in_quad4(Bx, By, Ax[k], Ay[k])) { vmask |= 1u << k; n++; }
    }
#pragma unroll
    for (int k = 0; k < 4; k++) {
        px[4 + k] = Bx[k]; py[4 + k] = By[k];
        if (pt_in_quad4(Ax, Ay, Bx[k], By[k])) { vmask |= 1u << (4 + k); n++; }
    }
#pragma unroll
    for (int k = 0; k < 4; k++) {
        int k1 = (k + 1) & 3;
        float rax = Ax[k1] - Ax[k], ray = Ay[k1] - Ay[k];
#pragma unroll
        for (int l = 0; l < 4; l++) {
            int l1 = (l + 1) & 3;
            float rbx = Bx[l1] - Bx[l], rby = By[l1] - By[l];
            float qpx = Bx[l] - Ax[k],  qpy = By[l] - Ay[k];
            float den = rax * rby - ray * rbx;
            float ad  = fabsf(den);
            float dsafe = (ad < 1e-9f) ? 1e-9f : den;
            float t = (qpx * rby - qpy * rbx) / dsafe;
            float u = (qpx * ray - qpy * rax) / dsafe;
            bool ok = (ad > 1e-9f) && t >= 0.f && t <= 1.f && u >= 0.f && u <= 1.f;
            int id = 8 + k * 4 + l;
            px[id] = Ax[k] + t * rax;
            py[id] = Ay[k] + t * ray;
            if (ok) { vmask |= 1u << id; n++; }
        }
    }
    float cx = 0.f, cy = 0.f;
#pragma unroll
    for (int m = 0; m < 24; m++)
        if ((vmask >> m) & 1u) { cx += px[m]; cy += py[m]; }
    int mx = (n < 1) ? 1 : n;
    cx = cx / (float)mx;
    cy = cy / (float)mx;

    unsigned long long key[32];
    float sx[32], sy[32];
#pragma unroll
    for (int m = 0; m < 24; m++) {
        float rx = px[m] - cx, ry = py[m] - cy;
        float a = ((vmask >> m) & 1u) ? atan2f(ry, rx) : 1e9f;
        unsigned u = __float_as_uint(a);
        u = (u & 0x80000000u) ? ~u : (u | 0x80000000u);
        key[m] = (((unsigned long long)u) << 6) | (unsigned)m;
        sx[m] = rx; sy[m] = ry;
    }
#pragma unroll
    for (int m = 24; m < 32; m++) { key[m] = ~0ull; sx[m] = 0.f; sy[m] = 0.f; }

#pragma unroll
    for (int k = 2; k <= 32; k <<= 1) {
#pragma unroll
        for (int j = k >> 1; j > 0; j >>= 1) {
#pragma unroll
            for (int t = 0; t < 32; t++) {
                int l = t ^ j;
                if (l > t) {
                    bool up = ((t & k) == 0);
                    bool sw = up ? (key[t] > key[l]) : (key[t] < key[l]);
                    if (sw) {
                        unsigned long long tk = key[t]; key[t] = key[l]; key[l] = tk;
                        float tx = sx[t]; sx[t] = sx[l]; sx[l] = tx;
                        float ty = sy[t]; sy[t] = sy[l]; sy[l] = ty;
                    }
                }
            }
        }
    }

    unsigned ut = __float_as_uint(1e9f) | 0x80000000u;
    unsigned long long kt = ((unsigned long long)ut) << 6;
    float fx = sx[0], fy = sy[0];
    float qx2[24], qy2[24];
#pragma unroll
    for (int m = 0; m < 24; m++) {
        bool v = key[m] < kt;
        qx2[m] = v ? sx[m] : fx;
        qy2[m] = v ? sy[m] : fy;
    }
    float ssum = 0.f;
#pragma unroll
    for (int m = 0; m < 24; m++) {
        int m1 = (m + 1) % 24;
        ssum += qx2[m] * qy2[m1] - qy2[m] * qx2[m1];
    }
    float area = 0.5f * fabsf(ssum);
    return (n >= 3) ? area : 0.f;
}

// compacted-index heavy test
__device__ bool iou_suppress_c(const float* __restrict__ co_cor,
                               const float* __restrict__ co_a5, int p, int q) {
    float Axr[4], Ayr[4], Bxr[4], Byr[4];
#pragma unroll
    for (int k = 0; k < 4; k++) {
        Axr[k] = co_cor[p * 8 + 2 * k]; Ayr[k] = co_cor[p * 8 + 2 * k + 1];
        Bxr[k] = co_cor[q * 8 + 2 * k]; Byr[k] = co_cor[q * 8 + 2 * k + 1];
    }
    float inter = quad_inter_area(Axr, Ayr, Bxr, Byr);
    float iou = inter / (co_a5[p] + co_a5[q] - inter + 1e-9f);
    return iou >= 0.2f;
}

__device__ __forceinline__ int sum_mcount(const int* __restrict__ mcount_w) {
    int M = 0;
#pragma unroll
    for (int k = 0; k < 21; k++) M += mcount_w[k];
    return M;
}

// ---------------- K1: decode ----------------
__global__ void k_decode(const float* __restrict__ out3, const float* __restrict__ out4,
                         const float* __restrict__ out5,
                         const float* __restrict__ o1l3, const float* __restrict__ o1l4,
                         const float* __restrict__ o1l5,
                         const float* __restrict__ ofl3, const float* __restrict__ ofl4,
                         const float* __restrict__ ofl5,
                         float* keyArr, float* cls0, float* cls1, float* xx, float* yy,
                         float* a5, float* ccx, float* ccy, float* rr,
                         float* rect, float* cor, int* mcount_w, int* done) {
    int n = blockIdx.x * blockDim.x + threadIdx.x;
    if (n >= N_DET) return;
    if (n == 0) *done = 0;   // ws is re-poisoned before every launch
    const float *out, *o1, *of;
    int w, idx; float stride;
    if (n < 1024)      { out = out3; o1 = o1l3; of = ofl3; w = 32; idx = n;        stride = 4.f; }
    else if (n < 1280) { out = out4; o1 = o1l4; of = ofl4; w = 16; idx = n - 1024; stride = 8.f; }
    else               { out = out5; o1 = o1l5; of = ofl5; w = 8;  idx = n - 1280; stride = 16.f; }
    int hw = w * w;
    int row = idx / w, col = idx % w;
    float cf = out[0 * hw + idx];
    float c0 = out[1 * hw + idx];
    float c1 = out[2 * hw + idx];
    float x  = out[3 * hw + idx] * stride + stride * (float)col;
    float y  = out[4 * hw + idx] * stride + stride * (float)row;

    float Pa[9], Pb[9];
    float minb = INFINITY, maxb = -INFINITY, mina = INFINITY, maxa = -INFINITY;
#pragma unroll
    for (int k = 0; k < 9; k++) {
        float a = of[(2 * k) * hw + idx]     + o1[(2 * k) * hw + idx]     + y;
        float b = of[(2 * k + 1) * hw + idx] + o1[(2 * k + 1) * hw + idx] + x;
        Pa[k] = a; Pb[k] = b;
        mina = fminf(mina, a); maxa = fmaxf(maxa, a);
        minb = fminf(minb, b); maxb = fmaxf(maxb, b);
    }
    float area = (maxb - minb) * (maxa - mina) / 40.0f;
    float sg = 1.0f / (1.0f + expf(-area));
    int m = (cf > 0.7f * sg) ? 1 : 0;

    float best = INFINITY, bc = 0.f, bs = 0.f;
    float bumin = 0.f, bumax = 0.f, bvmin = 0.f, bvmax = 0.f;
#pragma unroll
    for (int i = 0; i < 9; i++) {
#pragma unroll
        for (int j = i + 1; j < 9; j++) {
            float d0 = Pa[j] - Pa[i], d1 = Pb[j] - Pb[i];
            float nr = sqrtf(d0 * d0 + d1 * d1 + 1e-12f);
            float c = d0 / nr, s = d1 / nr;
            float umin = INFINITY, umax = -INFINITY, vmin = INFINITY, vmax = -INFINITY;
#pragma unroll
            for (int k = 0; k < 9; k++) {
                float u =  Pa[k] * c + Pb[k] * s;
                float v = -Pa[k] * s + Pb[k] * c;
                umin = fminf(umin, u); umax = fmaxf(umax, u);
                vmin = fminf(vmin, v); vmax = fmaxf(vmax, v);
            }
            float ar = (umax - umin) * (vmax - vmin);
            if (ar < best) { best = ar; bc = c; bs = s;
                             bumin = umin; bumax = umax; bvmin = vmin; bvmax = vmax; }
        }
    }
    float cu[4] = {bumin, bumax, bumax, bumin};
    float cv[4] = {bvmin, bvmin, bvmax, bvmax};
    float r8[8];
#pragma unroll
    for (int k = 0; k < 4; k++) {
        r8[2 * k]     = cu[k] * bc - cv[k] * bs;
        r8[2 * k + 1] = cu[k] * bs + cv[k] * bc;
    }
    float w5 = sqrtf((r8[0] - r8[2]) * (r8[0] - r8[2]) + (r8[1] - r8[3]) * (r8[1] - r8[3]));
    float h5 = sqrtf((r8[4] - r8[2]) * (r8[4] - r8[2]) + (r8[5] - r8[3]) * (r8[5] - r8[3]));
    float cx = (r8[1] + r8[3] + r8[5] + r8[7]) * 0.25f;
    float cy = (r8[0] + r8[2] + r8[4] + r8[6]) * 0.25f;
    float ang = atanf((r8[0] - r8[2]) / (r8[1] - r8[3]));
    float cs = cosf(ang), sn = sinf(ang);
    const float lxs[4] = {-0.5f, 0.5f, 0.5f, -0.5f};
    const float lys[4] = {-0.5f, -0.5f, 0.5f, 0.5f};
#pragma unroll
    for (int k = 0; k < 4; k++) {
        cor[n * 8 + 2 * k]     = cx + lxs[k] * w5 * cs - lys[k] * h5 * sn;
        cor[n * 8 + 2 * k + 1] = cy + lxs[k] * w5 * sn + lys[k] * h5 * cs;
    }
#pragma unroll
    for (int k = 0; k < 8; k++) rect[n * 8 + k] = r8[k];
    keyArr[n] = m ? cf : -INFINITY;
    cls0[n] = c0; cls1[n] = c1;
    xx[n] = x; yy[n] = y; a5[n] = w5 * h5;
    ccx[n] = cx; ccy[n] = cy;
    rr[n] = 0.5f * sqrtf(w5 * w5 + h5 * h5);   // circumradius (conservative prefilter only)
    unsigned long long mb = __ballot(m != 0);
    if ((threadIdx.x & 63) == 0) mcount_w[n >> 6] = (int)__popcll(mb);
}

// ---------------- K2: rank + compacted-layout copy (wave per candidate, 4/block) ----------------
__global__ __launch_bounds__(256) void k_order(
        const float* __restrict__ keyArr,
        const float* __restrict__ xx, const float* __restrict__ yy,
        const float* __restrict__ a5, const float* __restrict__ ccx,
        const float* __restrict__ ccy, const float* __restrict__ rr,
        const float* __restrict__ rect, const float* __restrict__ cor,
        int* order,
        float* co_ccx, float* co_ccy, float* co_rr, float* co_a5,
        float* co_xx, float* co_yy, float* co_rect, float* co_cor) {
    int lane = threadIdx.x & 63;
    int b = blockIdx.x * 4 + (threadIdx.x >> 6);   // candidate, grid 336*4 = 1344
    float ki = keyArr[b];
    int rank = 0;
    for (int j = lane; j < N_DET; j += 64) {
        float kj = keyArr[j];
        rank += ((kj > ki) || (kj == ki && j > b)) ? 1 : 0;   // reversed-stable
    }
    for (int off = 32; off; off >>= 1) rank += __shfl_down(rank, off, 64);
    rank = __shfl(rank, 0, 64);
    if (lane == 0)           order[rank] = b;
    if (lane < 8)            co_cor[rank * 8 + lane]        = cor[b * 8 + lane];
    else if (lane < 16)      co_rect[rank * 8 + (lane - 8)] = rect[b * 8 + (lane - 8)];
    else if (lane == 16)     co_ccx[rank] = ccx[b];
    else if (lane == 17)     co_ccy[rank] = ccy[b];
    else if (lane == 18)     co_rr[rank]  = rr[b];
    else if (lane == 19)     co_a5[rank]  = a5[b];
    else if (lane == 20)     co_xx[rank]  = xx[b];
    else if (lane == 21)     co_yy[rank]  = yy[b];
}

// ---------------- K3: fused pairs + (last-block) scan/output ----------------
__global__ __launch_bounds__(256) void k_pairs_scan(
        const float* __restrict__ co_rect, const float* __restrict__ co_cor,
        const float* __restrict__ co_a5,
        const float* __restrict__ co_xx, const float* __restrict__ co_yy,
        const float* __restrict__ co_ccx, const float* __restrict__ co_ccy,
        const float* __restrict__ co_rr,
        const float* __restrict__ cls0, const float* __restrict__ cls1,
        const float* __restrict__ xx, const float* __restrict__ yy,
        const float* __restrict__ rect,
        const int* __restrict__ order, const int* __restrict__ mcount_w,
        unsigned long long* __restrict__ S2, int* __restrict__ done,
        float* __restrict__ out) {
    __shared__ unsigned int queue[QCAP];
    __shared__ int qn;
    __shared__ int is_last;
    __shared__ unsigned long long T2[512 * T2S];
    __shared__ unsigned long long Kfin[MW_MAX];
    __shared__ unsigned int keep32[(N_DET + 31) / 32];
    __shared__ int cnt_s[2];

    int M = sum_mcount(mcount_w);
    int MW = (M + 63) >> 6;
    bool fast = (MW <= MW_MAX);
    int tid = threadIdx.x;
    int lane = tid & 63;
    int wid = tid >> 6;          // 4 waves
    if (tid == 0) qn = 0;
    __syncthreads();

    // ---------- pairs phase ----------
    if (M > 0) {
        int gwave = (blockIdx.x * 256 + tid) >> 6;
        int nwave = (gridDim.x * 256) >> 6;
        int total = M * MW;
        for (int t = gwave; t < total; t += nwave) {
            int p = t / MW;
            int w = t - p * MW;
            int q = w * 64 + lane;
            bool valid = q < M;
            int qc = valid ? q : 0;

            float cbi = co_ccx[p], cai = co_ccy[p], ri = co_rr[p];
            float pjy = co_yy[qc], pjx = co_xx[qc];
            float da = pjy - cai, db = pjx - cbi;
            float rin = ri + 0.1f;
            bool inside = false;
            if (da * da + db * db <= rin * rin) {
                float qxr[4], qyr[4];
#pragma unroll
                for (int k = 0; k < 4; k++) { qxr[k] = co_rect[p * 8 + 2 * k]; qyr[k] = co_rect[p * 8 + 2 * k + 1]; }
                inside = pt_in_quad4(qxr, qyr, pjy, pjx);
            }
            bool bit = valid && inside;
            unsigned long long bb = __ballot(bit);

            float ex = cbi - co_ccx[qc], ey = cai - co_ccy[qc];
            float rs = ri + co_rr[qc] + 0.1f;
            bool needy = valid && (q != p) && !bit && (ex * ex + ey * ey <= rs * rs);

            if (fast) {
                if (lane == 0) S2[p * MW + w] = bb;
                unsigned long long pm = __ballot(needy);
                if (pm) {
                    int cw = __popcll(pm);
                    int base = 0;
                    if (lane == 0) base = atomicAdd(&qn, cw);
                    base = __shfl(base, 0, 64);
                    if (needy) {
                        int pos = base + __popcll(pm & ((1ull << lane) - 1ull));
                        if (pos < QCAP) {
                            queue[pos] = ((unsigned)p << 11) | (unsigned)q;
                        } else {
                            __threadfence();
                            if (iou_suppress_c(co_cor, co_a5, p, q))
                                atomicOr(&S2[p * MW + w], 1ull << (q & 63));
                        }
                    }
                }
            } else {
                bool supp = needy && iou_suppress_c(co_cor, co_a5, p, q);
                unsigned long long sb = __ballot(supp);
                if (lane == 0) S2[p * MW + w] = bb | sb;
            }
        }
    }
    __syncthreads();

    if (M > 0 && fast) {
        int cnt = qn; if (cnt > QCAP) cnt = QCAP;
        for (int t = tid; t < cnt; t += 256) {
            unsigned v = queue[t];
            int p = (int)(v >> 11), q = (int)(v & 2047u);
            if (iou_suppress_c(co_cor, co_a5, p, q))
                atomicOr(&S2[p * MW + (q >> 6)], 1ull << (q & 63));
        }
    }

    // ---------- arrive; last block runs the scan ----------
    __syncthreads();
    __threadfence();                       // release S2 writes (device scope)
    if (tid == 0) {
        int old = atomicAdd(done, 1);
        is_last = (old == (int)gridDim.x - 1) ? 1 : 0;
    }
    __syncthreads();
    if (!is_last) return;
    __threadfence();                       // acquire others' S2 writes

    // ---------- scan phase (single block, 256 threads) ----------
    for (int t = tid; t < (N_DET + 31) / 32; t += 256) keep32[t] = 0u;
    if (tid < 2) cnt_s[tid] = 0;
    if (tid < MW_MAX) Kfin[tid] = 0ull;
    __syncthreads();

    if (M > 0 && fast) {
        // bit-transpose S2 -> T2 (64x64 blocks via ballots), 4 waves
        for (int blk = wid; blk < MW * MW; blk += 4) {
            int wp = blk / MW, wq = blk - wp * MW;
            int pp = wp * 64 + lane;
            unsigned long long x = (pp < M) ? S2[pp * MW + wq] : 0ull;
#pragma unroll
            for (int b = 0; b < 64; b++) {
                unsigned long long bb = __ballot((x >> b) & 1ull);
                if (lane == b) T2[(wq * 64 + b) * T2S + wp] = bb;
            }
        }
        __syncthreads();

        // word-nested Gauss-Seidel fixed point (wave 0)
        if (wid == 0) {
            unsigned long long kw[MW_MAX];
            unsigned long long pmask = lane ? ((1ull << lane) - 1ull) : 0ull;
#pragma unroll
            for (int k = 0; k < MW_MAX; k++) {
                if (k < MW) {
                    int q = k * 64 + lane;
                    const unsigned long long* row = &T2[q * T2S];
                    unsigned long long base = 0ull;
#pragma unroll
                    for (int w = 0; w < MW_MAX; w++)
                        if (w < k) base |= row[w] & kw[w];
                    unsigned long long rk = row[k] & pmask;
                    bool qv = q < M;
                    int lo = k * 64;
                    unsigned long long cur =
                        (M - lo >= 64) ? ~0ull : ((1ull << (M - lo)) - 1ull);
                    for (int guard = 0; guard < 66; guard++) {
                        bool nb = qv && ((base | (rk & cur)) == 0ull);
                        unsigned long long nw = __ballot(nb);
                        if (nw == cur) break;
                        cur = nw;
                    }
                    kw[k] = cur;
                }
            }
            if (lane == 0) {
#pragma unroll
                for (int w = 0; w < MW_MAX; w++) Kfin[w] = (w < MW) ? kw[w] : 0ull;
            }
        }
        __syncthreads();
        for (int t = tid; t < M; t += 256) {
            if ((Kfin[t >> 6] >> (t & 63)) & 1ull) {
                int i = order[t];
                atomicOr(&keep32[i >> 5], 1u << (i & 31));
            }
        }
    } else if (M > 0) {
        // generic sequential fallback (M > 512)
        if (wid == 0) {
            unsigned long long rem = 0ull;
            int lo = lane * 64;
            if (M > lo) rem = (M - lo >= 64) ? ~0ull : ((1ull << (M - lo)) - 1ull);
            for (int guard = 0; guard < N_DET; guard++) {
                unsigned long long vote = __ballot(rem != 0ull);
                if (!vote) break;
                int w = __builtin_ctzll(vote);
                unsigned long long wd = __shfl(rem, w, 64);
                int b = __builtin_ctzll(wd);
                int p = w * 64 + b;
                int i = order[p];
                if (lane == 0) atomicOr(&keep32[i >> 5], 1u << (i & 31));
                unsigned long long rowv = (lane < MW) ? S2[p * MW + lane] : 0ull;
                rem &= ~rowv;
                if (lane == w) rem &= ~(1ull << b);
            }
        }
    }
    __syncthreads();

    int c0 = 0, c1 = 0;
    for (int n = tid; n < N_DET; n += 256) {
        bool kp = (keep32[n >> 5] >> (n & 31)) & 1u;
        float a = cls0[n], b = cls1[n];
        float mxc = fmaxf(a, b);
        bool m0 = kp && (a == mxc);
        bool m1 = kp && (b == mxc);
        float x = xx[n], y = yy[n];
        out[2 + 0 * N_DET * 2 + n * 2 + 0] = m0 ? x : 0.f;
        out[2 + 0 * N_DET * 2 + n * 2 + 1] = m0 ? y : 0.f;
        out[2 + 1 * N_DET * 2 + n * 2 + 0] = m1 ? x : 0.f;
        out[2 + 1 * N_DET * 2 + n * 2 + 1] = m1 ? y : 0.f;
        float kf = kp ? 1.f : 0.f;
#pragma unroll
        for (int k = 0; k < 8; k++)
            out[2 + 2 * N_DET * 2 + n * 8 + k] = rect[n * 8 + k] * kf;
        c0 += m0 ? 1 : 0;
        c1 += m1 ? 1 : 0;
    }
    if (c0) atomicAdd(&cnt_s[0], c0);
    if (c1) atomicAdd(&cnt_s[1], c1);
    __syncthreads();
    if (tid == 0) { out[0] = (float)cnt_s[0]; out[1] = (float)cnt_s[1]; }
}

// ---------------- launch ----------------
extern "C" void kernel_launch(void* const* d_in, const int* in_sizes, int n_in,
                              void* d_out, int out_size, void* d_ws, size_t ws_size,
                              hipStream_t stream) {
    const int N = N_DET;
    float* wsf = (float*)d_ws;

    const float* out3 = (const float*)d_in[0];
    const float* out4 = (const float*)d_in[1];
    const float* out5 = (const float*)d_in[2];
    const float* o1l3 = (const float*)d_in[3];
    const float* o1l4 = (const float*)d_in[4];
    const float* o1l5 = (const float*)d_in[5];
    const float* ofl3 = (const float*)d_in[6];
    const float* ofl4 = (const float*)d_in[7];
    const float* ofl5 = (const float*)d_in[8];
    float* out = (float*)d_out;

    float* keyArr = wsf + 0 * N;
    float* cls0   = wsf + 1 * N;
    float* cls1   = wsf + 2 * N;
    float* xx     = wsf + 3 * N;
    float* yy     = wsf + 4 * N;
    float* a5     = wsf + 5 * N;
    float* ccx    = wsf + 6 * N;
    float* ccy    = wsf + 7 * N;
    float* rr     = wsf + 8 * N;
    float* rect   = wsf + 9 * N;    // 8N
    float* cor    = wsf + 17 * N;   // 8N  -> ends 25N
    float* co_ccx = wsf + 25 * N;
    float* co_ccy = wsf + 26 * N;
    float* co_rr  = wsf + 27 * N;
    float* co_a5  = wsf + 28 * N;
    float* co_xx  = wsf + 29 * N;
    float* co_yy  = wsf + 30 * N;
    float* co_rect= wsf + 31 * N;   // 8N
    float* co_cor = wsf + 39 * N;   // 8N  -> ends 47N
    int* order    = (int*)(wsf + 47 * N);   // N
    int* mcount_w = order + N;              // 21
    int* done     = mcount_w + 21;          // 1 (+pad 2 to 8B align)
    unsigned long long* S2 = (unsigned long long*)(wsf + 48 * N + 24);  // up to N*21 u64

    k_decode<<<(N + 255) / 256, 256, 0, stream>>>(out3, out4, out5, o1l3, o1l4, o1l5,
                                                  ofl3, ofl4, ofl5,
                                                  keyArr, cls0, cls1, xx, yy, a5,
                                                  ccx, ccy, rr, rect, cor, mcount_w, done);
    k_order<<<N / 4, 256, 0, stream>>>(keyArr, xx, yy, a5, ccx, ccy, rr, rect, cor,
                                       order,
                                       co_ccx, co_ccy, co_rr, co_a5, co_xx, co_yy,
                                       co_rect, co_cor);
    k_pairs_scan<<<PAIR_BLOCKS, 256, 0, stream>>>(co_rect, co_cor, co_a5, co_xx, co_yy,
                                                  co_ccx, co_ccy, co_rr,
                                                  cls0, cls1, xx, yy, rect,
                                                  order, mcount_w, S2, done, out);
}

// Round 9
// 122.867 us; speedup vs baseline: 1.3041x; 1.3041x over previous
//
#include <hip/hip_runtime.h>
#include <math.h>

#define N_DET 1344
#define MW_MAX 8     // fast path supports M <= 512
#define T2S 9        // padded LDS row stride (u64) — breaks bank conflicts
#define QCAP 2048    // per-block needy-pair queue

// ---------------- device helpers ----------------

__device__ __forceinline__ bool pt_in_quad4(const float* qx, const float* qy,
                                            float px, float py) {
    bool allp = true, alln = true;
#pragma unroll
    for (int k = 0; k < 4; k++) {
        int k1 = (k + 1) & 3;
        float ex = qx[k1] - qx[k], ey = qy[k1] - qy[k];
        float rx = px - qx[k],     ry = py - qy[k];
        float cr = ex * ry - ey * rx;
        allp = allp && (cr >= 0.f);
        alln = alln && (cr <= 0.f);
    }
    return allp || alln;
}

// Exact fp-order-matched intersection area (register-only bitonic sort).
__device__ float quad_inter_area(const float* Ax, const float* Ay,
                                 const float* Bx, const float* By) {
    float px[24], py[24];
    unsigned vmask = 0;
    int n = 0;
#pragma unroll
    for (int k = 0; k < 4; k++) {
        px[k] = Ax[k]; py[k] = Ay[k];
        if (pt_in_quad4(Bx, By, Ax[k], Ay[k])) { vmask |= 1u << k; n++; }
    }
#pragma unroll
    for (int k = 0; k < 4; k++) {
        px[4 + k] = Bx[k]; py[4 + k] = By[k];
        if (pt_in_quad4(Ax, Ay, Bx[k], By[k])) { vmask |= 1u << (4 + k); n++; }
    }
#pragma unroll
    for (int k = 0; k < 4; k++) {
        int k1 = (k + 1) & 3;
        float rax = Ax[k1] - Ax[k], ray = Ay[k1] - Ay[k];
#pragma unroll
        for (int l = 0; l < 4; l++) {
            int l1 = (l + 1) & 3;
            float rbx = Bx[l1] - Bx[l], rby = By[l1] - By[l];
            float qpx = Bx[l] - Ax[k],  qpy = By[l] - Ay[k];
            float den = rax * rby - ray * rbx;
            float ad  = fabsf(den);
            float dsafe = (ad < 1e-9f) ? 1e-9f : den;
            float t = (qpx * rby - qpy * rbx) / dsafe;
            float u = (qpx * ray - qpy * rax) / dsafe;
            bool ok = (ad > 1e-9f) && t >= 0.f && t <= 1.f && u >= 0.f && u <= 1.f;
            int id = 8 + k * 4 + l;
            px[id] = Ax[k] + t * rax;
            py[id] = Ay[k] + t * ray;
            if (ok) { vmask |= 1u << id; n++; }
        }
    }
    float cx = 0.f, cy = 0.f;
#pragma unroll
    for (int m = 0; m < 24; m++)
        if ((vmask >> m) & 1u) { cx += px[m]; cy += py[m]; }
    int mx = (n < 1) ? 1 : n;
    cx = cx / (float)mx;
    cy = cy / (float)mx;

    unsigned long long key[32];
    float sx[32], sy[32];
#pragma unroll
    for (int m = 0; m < 24; m++) {
        float rx = px[m] - cx, ry = py[m] - cy;
        float a = ((vmask >> m) & 1u) ? atan2f(ry, rx) : 1e9f;
        unsigned u = __float_as_uint(a);
        u = (u & 0x80000000u) ? ~u : (u | 0x80000000u);
        key[m] = (((unsigned long long)u) << 6) | (unsigned)m;
        sx[m] = rx; sy[m] = ry;
    }
#pragma unroll
    for (int m = 24; m < 32; m++) { key[m] = ~0ull; sx[m] = 0.f; sy[m] = 0.f; }

#pragma unroll
    for (int k = 2; k <= 32; k <<= 1) {
#pragma unroll
        for (int j = k >> 1; j > 0; j >>= 1) {
#pragma unroll
            for (int t = 0; t < 32; t++) {
                int l = t ^ j;
                if (l > t) {
                    bool up = ((t & k) == 0);
                    bool sw = up ? (key[t] > key[l]) : (key[t] < key[l]);
                    if (sw) {
                        unsigned long long tk = key[t]; key[t] = key[l]; key[l] = tk;
                        float tx = sx[t]; sx[t] = sx[l]; sx[l] = tx;
                        float ty = sy[t]; sy[t] = sy[l]; sy[l] = ty;
                    }
                }
            }
        }
    }

    unsigned ut = __float_as_uint(1e9f) | 0x80000000u;
    unsigned long long kt = ((unsigned long long)ut) << 6;
    float fx = sx[0], fy = sy[0];
    float qx2[24], qy2[24];
#pragma unroll
    for (int m = 0; m < 24; m++) {
        bool v = key[m] < kt;
        qx2[m] = v ? sx[m] : fx;
        qy2[m] = v ? sy[m] : fy;
    }
    float ssum = 0.f;
#pragma unroll
    for (int m = 0; m < 24; m++) {
        int m1 = (m + 1) % 24;
        ssum += qx2[m] * qy2[m1] - qy2[m] * qx2[m1];
    }
    float area = 0.5f * fabsf(ssum);
    return (n >= 3) ? area : 0.f;
}

// compacted-index heavy test
__device__ bool iou_suppress_c(const float* __restrict__ co_cor,
                               const float* __restrict__ co_a5, int p, int q) {
    float Axr[4], Ayr[4], Bxr[4], Byr[4];
#pragma unroll
    for (int k = 0; k < 4; k++) {
        Axr[k] = co_cor[p * 8 + 2 * k]; Ayr[k] = co_cor[p * 8 + 2 * k + 1];
        Bxr[k] = co_cor[q * 8 + 2 * k]; Byr[k] = co_cor[q * 8 + 2 * k + 1];
    }
    float inter = quad_inter_area(Axr, Ayr, Bxr, Byr);
    float iou = inter / (co_a5[p] + co_a5[q] - inter + 1e-9f);
    return iou >= 0.2f;
}

__device__ __forceinline__ int sum_mcount(const int* __restrict__ mcount_w) {
    int M = 0;
#pragma unroll
    for (int k = 0; k < 21; k++) M += mcount_w[k];
    return M;
}

// ---------------- K1: decode ----------------
__global__ void k_decode(const float* __restrict__ out3, const float* __restrict__ out4,
                         const float* __restrict__ out5,
                         const float* __restrict__ o1l3, const float* __restrict__ o1l4,
                         const float* __restrict__ o1l5,
                         const float* __restrict__ ofl3, const float* __restrict__ ofl4,
                         const float* __restrict__ ofl5,
                         float* keyArr, float* cls0, float* cls1, float* xx, float* yy,
                         float* a5, float* ccx, float* ccy, float* rr,
                         float* rect, float* cor, int* mcount_w) {
    int n = blockIdx.x * blockDim.x + threadIdx.x;
    if (n >= N_DET) return;
    const float *out, *o1, *of;
    int w, idx; float stride;
    if (n < 1024)      { out = out3; o1 = o1l3; of = ofl3; w = 32; idx = n;        stride = 4.f; }
    else if (n < 1280) { out = out4; o1 = o1l4; of = ofl4; w = 16; idx = n - 1024; stride = 8.f; }
    else               { out = out5; o1 = o1l5; of = ofl5; w = 8;  idx = n - 1280; stride = 16.f; }
    int hw = w * w;
    int row = idx / w, col = idx % w;
    float cf = out[0 * hw + idx];
    float c0 = out[1 * hw + idx];
    float c1 = out[2 * hw + idx];
    float x  = out[3 * hw + idx] * stride + stride * (float)col;
    float y  = out[4 * hw + idx] * stride + stride * (float)row;

    float Pa[9], Pb[9];
    float minb = INFINITY, maxb = -INFINITY, mina = INFINITY, maxa = -INFINITY;
#pragma unroll
    for (int k = 0; k < 9; k++) {
        float a = of[(2 * k) * hw + idx]     + o1[(2 * k) * hw + idx]     + y;
        float b = of[(2 * k + 1) * hw + idx] + o1[(2 * k + 1) * hw + idx] + x;
        Pa[k] = a; Pb[k] = b;
        mina = fminf(mina, a); maxa = fmaxf(maxa, a);
        minb = fminf(minb, b); maxb = fmaxf(maxb, b);
    }
    float area = (maxb - minb) * (maxa - mina) / 40.0f;
    float sg = 1.0f / (1.0f + expf(-area));
    int m = (cf > 0.7f * sg) ? 1 : 0;

    float best = INFINITY, bc = 0.f, bs = 0.f;
    float bumin = 0.f, bumax = 0.f, bvmin = 0.f, bvmax = 0.f;
#pragma unroll
    for (int i = 0; i < 9; i++) {
#pragma unroll
        for (int j = i + 1; j < 9; j++) {
            float d0 = Pa[j] - Pa[i], d1 = Pb[j] - Pb[i];
            float nr = sqrtf(d0 * d0 + d1 * d1 + 1e-12f);
            float c = d0 / nr, s = d1 / nr;
            float umin = INFINITY, umax = -INFINITY, vmin = INFINITY, vmax = -INFINITY;
#pragma unroll
            for (int k = 0; k < 9; k++) {
                float u =  Pa[k] * c + Pb[k] * s;
                float v = -Pa[k] * s + Pb[k] * c;
                umin = fminf(umin, u); umax = fmaxf(umax, u);
                vmin = fminf(vmin, v); vmax = fmaxf(vmax, v);
            }
            float ar = (umax - umin) * (vmax - vmin);
            if (ar < best) { best = ar; bc = c; bs = s;
                             bumin = umin; bumax = umax; bvmin = vmin; bvmax = vmax; }
        }
    }
    float cu[4] = {bumin, bumax, bumax, bumin};
    float cv[4] = {bvmin, bvmin, bvmax, bvmax};
    float r8[8];
#pragma unroll
    for (int k = 0; k < 4; k++) {
        r8[2 * k]     = cu[k] * bc - cv[k] * bs;
        r8[2 * k + 1] = cu[k] * bs + cv[k] * bc;
    }
    float w5 = sqrtf((r8[0] - r8[2]) * (r8[0] - r8[2]) + (r8[1] - r8[3]) * (r8[1] - r8[3]));
    float h5 = sqrtf((r8[4] - r8[2]) * (r8[4] - r8[2]) + (r8[5] - r8[3]) * (r8[5] - r8[3]));
    float cx = (r8[1] + r8[3] + r8[5] + r8[7]) * 0.25f;
    float cy = (r8[0] + r8[2] + r8[4] + r8[6]) * 0.25f;
    float ang = atanf((r8[0] - r8[2]) / (r8[1] - r8[3]));
    float cs = cosf(ang), sn = sinf(ang);
    const float lxs[4] = {-0.5f, 0.5f, 0.5f, -0.5f};
    const float lys[4] = {-0.5f, -0.5f, 0.5f, 0.5f};
#pragma unroll
    for (int k = 0; k < 4; k++) {
        cor[n * 8 + 2 * k]     = cx + lxs[k] * w5 * cs - lys[k] * h5 * sn;
        cor[n * 8 + 2 * k + 1] = cy + lxs[k] * w5 * sn + lys[k] * h5 * cs;
    }
#pragma unroll
    for (int k = 0; k < 8; k++) rect[n * 8 + k] = r8[k];
    keyArr[n] = m ? cf : -INFINITY;
    cls0[n] = c0; cls1[n] = c1;
    xx[n] = x; yy[n] = y; a5[n] = w5 * h5;
    ccx[n] = cx; ccy[n] = cy;
    rr[n] = 0.5f * sqrtf(w5 * w5 + h5 * h5);   // circumradius (conservative prefilter only)
    // per-wave masked count (waves 0..20 all fully active: 1344 = 21*64)
    unsigned long long mb = __ballot(m != 0);
    if ((threadIdx.x & 63) == 0) mcount_w[n >> 6] = (int)__popcll(mb);
}

// ---------------- K2: rank + compacted-layout copy (wave per candidate, 4/block) ----------------
__global__ __launch_bounds__(256) void k_order(
        const float* __restrict__ keyArr,
        const float* __restrict__ xx, const float* __restrict__ yy,
        const float* __restrict__ a5, const float* __restrict__ ccx,
        const float* __restrict__ ccy, const float* __restrict__ rr,
        const float* __restrict__ rect, const float* __restrict__ cor,
        int* order,
        float* co_ccx, float* co_ccy, float* co_rr, float* co_a5,
        float* co_xx, float* co_yy, float* co_rect, float* co_cor) {
    int lane = threadIdx.x & 63;
    int b = blockIdx.x * 4 + (threadIdx.x >> 6);   // candidate, grid 336*4 = 1344
    float ki = keyArr[b];
    int rank = 0;
    for (int j = lane; j < N_DET; j += 64) {
        float kj = keyArr[j];
        rank += ((kj > ki) || (kj == ki && j > b)) ? 1 : 0;   // reversed-stable
    }
    for (int off = 32; off; off >>= 1) rank += __shfl_down(rank, off, 64);
    rank = __shfl(rank, 0, 64);
    if (lane == 0)           order[rank] = b;
    if (lane < 8)            co_cor[rank * 8 + lane]        = cor[b * 8 + lane];
    else if (lane < 16)      co_rect[rank * 8 + (lane - 8)] = rect[b * 8 + (lane - 8)];
    else if (lane == 16)     co_ccx[rank] = ccx[b];
    else if (lane == 17)     co_ccy[rank] = ccy[b];
    else if (lane == 18)     co_rr[rank]  = rr[b];
    else if (lane == 19)     co_a5[rank]  = a5[b];
    else if (lane == 20)     co_xx[rank]  = xx[b];
    else if (lane == 21)     co_yy[rank]  = yy[b];
}

// ---------------- K3: fused prefilter + inside bits + in-block heavy pairs ----------------
__global__ __launch_bounds__(256) void k_pairs(
        const float* __restrict__ co_rect, const float* __restrict__ co_cor,
        const float* __restrict__ co_a5,
        const float* __restrict__ co_xx, const float* __restrict__ co_yy,
        const float* __restrict__ co_ccx, const float* __restrict__ co_ccy,
        const float* __restrict__ co_rr,
        const int* __restrict__ mcount_w, unsigned long long* __restrict__ S2) {
    __shared__ unsigned int queue[QCAP];
    __shared__ int qn;
    int M = sum_mcount(mcount_w);
    int MW = (M + 63) >> 6;
    bool fast = (MW <= MW_MAX);
    int tid = threadIdx.x;
    int lane = tid & 63;
    if (tid == 0) qn = 0;
    __syncthreads();

    if (M > 0) {
        int gwave = (blockIdx.x * 256 + tid) >> 6;
        int nwave = (gridDim.x * 256) >> 6;
        int total = M * MW;
        for (int t = gwave; t < total; t += nwave) {
            int p = t / MW;
            int w = t - p * MW;
            int q = w * 64 + lane;
            bool valid = q < M;
            int qc = valid ? q : 0;

            float cbi = co_ccx[p], cai = co_ccy[p], ri = co_rr[p];
            float pjy = co_yy[qc], pjx = co_xx[qc];
            float da = pjy - cai, db = pjx - cbi;
            float rin = ri + 0.1f;
            bool inside = false;
            if (da * da + db * db <= rin * rin) {
                float qxr[4], qyr[4];
#pragma unroll
                for (int k = 0; k < 4; k++) { qxr[k] = co_rect[p * 8 + 2 * k]; qyr[k] = co_rect[p * 8 + 2 * k + 1]; }
                inside = pt_in_quad4(qxr, qyr, pjy, pjx);
            }
            bool bit = valid && inside;
            unsigned long long bb = __ballot(bit);

            float ex = cbi - co_ccx[qc], ey = cai - co_ccy[qc];
            float rs = ri + co_rr[qc] + 0.1f;
            bool needy = valid && (q != p) && !bit && (ex * ex + ey * ey <= rs * rs);

            if (fast) {
                if (lane == 0) S2[p * MW + w] = bb;
                unsigned long long pm = __ballot(needy);
                if (pm) {
                    int cw = __popcll(pm);
                    int base = 0;
                    if (lane == 0) base = atomicAdd(&qn, cw);
                    base = __shfl(base, 0, 64);
                    if (needy) {
                        int pos = base + __popcll(pm & ((1ull << lane) - 1ull));
                        if (pos < QCAP) {
                            queue[pos] = ((unsigned)p << 11) | (unsigned)q;
                        } else {
                            // overflow (practically never): compute inline.
                            __threadfence();   // order after our wave's ballot store
                            if (iou_suppress_c(co_cor, co_a5, p, q))
                                atomicOr(&S2[p * MW + w], 1ull << (q & 63));
                        }
                    }
                }
            } else {
                // fallback: compute heavy test inline, single combined store, no atomics
                bool supp = needy && iou_suppress_c(co_cor, co_a5, p, q);
                unsigned long long sb = __ballot(supp);
                if (lane == 0) S2[p * MW + w] = bb | sb;
            }
        }
    }
    __syncthreads();

    if (M > 0 && fast) {
        int cnt = qn; if (cnt > QCAP) cnt = QCAP;
        for (int t = tid; t < cnt; t += 256) {
            unsigned v = queue[t];
            int p = (int)(v >> 11), q = (int)(v & 2047u);
            if (iou_suppress_c(co_cor, co_a5, p, q))
                atomicOr(&S2[p * MW + (q >> 6)], 1ull << (q & 63));
        }
    }
}

// ---------------- K4: transpose + word-nested Gauss-Seidel NMS + outputs ----------------
__global__ __launch_bounds__(512) void k_scan_out(
    const float* __restrict__ cls0, const float* __restrict__ cls1,
    const float* __restrict__ xx, const float* __restrict__ yy,
    const float* __restrict__ rect,
    const int* __restrict__ order, const int* __restrict__ mcount_w,
    const unsigned long long* __restrict__ S2, float* __restrict__ out) {
    __shared__ unsigned long long T2[512 * T2S];
    __shared__ unsigned long long Kfin[MW_MAX];
    __shared__ unsigned int keep32[(N_DET + 31) / 32];
    __shared__ int cnt_s[2];
    int tid = threadIdx.x;
    int lane = tid & 63, wid = tid >> 6;   // 8 waves
    int M = sum_mcount(mcount_w);
    int MW = (M + 63) >> 6;
    for (int t = tid; t < (N_DET + 31) / 32; t += 512) keep32[t] = 0u;
    if (tid < 2) cnt_s[tid] = 0;
    if (tid < MW_MAX) Kfin[tid] = 0ull;
    __syncthreads();

    if (M > 0 && MW <= MW_MAX) {
        // bit-transpose S2 -> T2 (64x64 blocks via ballots), 8 waves
        for (int blk = wid; blk < MW * MW; blk += 8) {
            int wp = blk / MW, wq = blk - wp * MW;
            int pp = wp * 64 + lane;
            unsigned long long x = (pp < M) ? S2[pp * MW + wq] : 0ull;
#pragma unroll
            for (int b = 0; b < 64; b++) {
                unsigned long long bb = __ballot((x >> b) & 1ull);
                if (lane == b) T2[(wq * 64 + b) * T2S + wp] = bb;
            }
        }
        __syncthreads();

        // word-nested Gauss-Seidel: finalize word k, then k+1 (cross-word deps forward-only).
        if (wid == 0) {
            unsigned long long kw[MW_MAX];
            unsigned long long pmask = lane ? ((1ull << lane) - 1ull) : 0ull;
#pragma unroll
            for (int k = 0; k < MW_MAX; k++) {
                if (k < MW) {
                    int q = k * 64 + lane;
                    const unsigned long long* row = &T2[q * T2S];
                    unsigned long long base = 0ull;
#pragma unroll
                    for (int w = 0; w < MW_MAX; w++)
                        if (w < k) base |= row[w] & kw[w];
                    unsigned long long rk = row[k] & pmask;
                    bool qv = q < M;
                    int lo = k * 64;
                    unsigned long long cur =
                        (M - lo >= 64) ? ~0ull : ((1ull << (M - lo)) - 1ull);
                    for (int guard = 0; guard < 66; guard++) {
                        bool nb = qv && ((base | (rk & cur)) == 0ull);
                        unsigned long long nw = __ballot(nb);
                        if (nw == cur) break;
                        cur = nw;
                    }
                    kw[k] = cur;
                }
            }
            if (lane == 0) {
#pragma unroll
                for (int w = 0; w < MW_MAX; w++) Kfin[w] = (w < MW) ? kw[w] : 0ull;
            }
        }
        __syncthreads();
        for (int t = tid; t < M; t += 512) {
            if ((Kfin[t >> 6] >> (t & 63)) & 1ull) {
                int i = order[t];
                atomicOr(&keep32[i >> 5], 1u << (i & 31));
            }
        }
    } else if (M > 0) {
        // generic sequential fallback (M > 512)
        if (wid == 0) {
            unsigned long long rem = 0ull;
            int lo = lane * 64;
            if (M > lo) rem = (M - lo >= 64) ? ~0ull : ((1ull << (M - lo)) - 1ull);
            for (int guard = 0; guard < N_DET; guard++) {
                unsigned long long vote = __ballot(rem != 0ull);
                if (!vote) break;
                int w = __builtin_ctzll(vote);
                unsigned long long wd = __shfl(rem, w, 64);
                int b = __builtin_ctzll(wd);
                int p = w * 64 + b;
                int i = order[p];
                if (lane == 0) atomicOr(&keep32[i >> 5], 1u << (i & 31));
                unsigned long long rowv = (lane < MW) ? S2[p * MW + lane] : 0ull;
                rem &= ~rowv;
                if (lane == w) rem &= ~(1ull << b);
            }
        }
    }
    __syncthreads();

    int c0 = 0, c1 = 0;
    for (int n = tid; n < N_DET; n += 512) {
        bool kp = (keep32[n >> 5] >> (n & 31)) & 1u;
        float a = cls0[n], b = cls1[n];
        float mxc = fmaxf(a, b);
        bool m0 = kp && (a == mxc);
        bool m1 = kp && (b == mxc);
        float x = xx[n], y = yy[n];
        out[2 + 0 * N_DET * 2 + n * 2 + 0] = m0 ? x : 0.f;
        out[2 + 0 * N_DET * 2 + n * 2 + 1] = m0 ? y : 0.f;
        out[2 + 1 * N_DET * 2 + n * 2 + 0] = m1 ? x : 0.f;
        out[2 + 1 * N_DET * 2 + n * 2 + 1] = m1 ? y : 0.f;
        float kf = kp ? 1.f : 0.f;
#pragma unroll
        for (int k = 0; k < 8; k++)
            out[2 + 2 * N_DET * 2 + n * 8 + k] = rect[n * 8 + k] * kf;
        c0 += m0 ? 1 : 0;
        c1 += m1 ? 1 : 0;
    }
    if (c0) atomicAdd(&cnt_s[0], c0);
    if (c1) atomicAdd(&cnt_s[1], c1);
    __syncthreads();
    if (tid == 0) { out[0] = (float)cnt_s[0]; out[1] = (float)cnt_s[1]; }
}

// ---------------- launch ----------------
extern "C" void kernel_launch(void* const* d_in, const int* in_sizes, int n_in,
                              void* d_out, int out_size, void* d_ws, size_t ws_size,
                              hipStream_t stream) {
    const int N = N_DET;
    float* wsf = (float*)d_ws;

    const float* out3 = (const float*)d_in[0];
    const float* out4 = (const float*)d_in[1];
    const float* out5 = (const float*)d_in[2];
    const float* o1l3 = (const float*)d_in[3];
    const float* o1l4 = (const float*)d_in[4];
    const float* o1l5 = (const float*)d_in[5];
    const float* ofl3 = (const float*)d_in[6];
    const float* ofl4 = (const float*)d_in[7];
    const float* ofl5 = (const float*)d_in[8];
    float* out = (float*)d_out;

    float* keyArr = wsf + 0 * N;
    float* cls0   = wsf + 1 * N;
    float* cls1   = wsf + 2 * N;
    float* xx     = wsf + 3 * N;
    float* yy     = wsf + 4 * N;
    float* a5     = wsf + 5 * N;
    float* ccx    = wsf + 6 * N;
    float* ccy    = wsf + 7 * N;
    float* rr     = wsf + 8 * N;
    float* rect   = wsf + 9 * N;    // 8N
    float* cor    = wsf + 17 * N;   // 8N  -> ends 25N
    float* co_ccx = wsf + 25 * N;
    float* co_ccy = wsf + 26 * N;
    float* co_rr  = wsf + 27 * N;
    float* co_a5  = wsf + 28 * N;
    float* co_xx  = wsf + 29 * N;
    float* co_yy  = wsf + 30 * N;
    float* co_rect= wsf + 31 * N;   // 8N
    float* co_cor = wsf + 39 * N;   // 8N  -> ends 47N
    int* order    = (int*)(wsf + 47 * N);   // N
    int* mcount_w = order + N;              // 21 (+pad 3)
    unsigned long long* S2 = (unsigned long long*)(wsf + 48 * N + 24);  // up to N*21 u64

    k_decode<<<(N + 255) / 256, 256, 0, stream>>>(out3, out4, out5, o1l3, o1l4, o1l5,
                                                  ofl3, ofl4, ofl5,
                                                  keyArr, cls0, cls1, xx, yy, a5,
                                                  ccx, ccy, rr, rect, cor, mcount_w);
    k_order<<<N / 4, 256, 0, stream>>>(keyArr, xx, yy, a5, ccx, ccy, rr, rect, cor,
                                       order,
                                       co_ccx, co_ccy, co_rr, co_a5, co_xx, co_yy,
                                       co_rect, co_cor);
    k_pairs<<<256, 256, 0, stream>>>(co_rect, co_cor, co_a5, co_xx, co_yy,
                                     co_ccx, co_ccy, co_rr, mcount_w, S2);
    k_scan_out<<<1, 512, 0, stream>>>(cls0, cls1, xx, yy, rect, order, mcount_w, S2, out);
}